// Round 3
// baseline (44.822 us; speedup 1.0000x reference)
//
#include <hip/hip_runtime.h>

typedef short bf16x8 __attribute__((ext_vector_type(8)));
typedef float f32x4  __attribute__((ext_vector_type(4)));

#define HN    32
#define CIN   64
#define KP    27
#define QB    64          // queries per block (old fallback path)
#define CAPB  96          // entry slots per block (old fallback path)
#define NTB   1024        // 16 waves (old fallback path)
#define OSTR  65          // outacc stride (old fallback path)

// fused path
#define QB2   64          // queries per fused block (2048 pairs)
#define CAP2  128         // survivor capacity (mean 54, sigma 7.3 -> +10 sigma)
#define OSTR2 68          // outacc stride: 16B-aligned float4 rows, bank-skewed

#define INV_EXT 1.1547005383792517f   // 1/0.8660254
#define CUT2    3.4821f               // (1+0.8660254)^2 padded (extras get w=0)

__device__ __forceinline__ unsigned f2bf(float f){
    union{float fv;unsigned u;}v; v.fv=f;
    unsigned u=v.u;
    u += 0x7fffu + ((u>>16)&1u);      // RNE
    return u>>16;
}

// ---------------- pack kernels -------------------------------------------
__global__ void pack_spts(const float* __restrict__ s, float4* __restrict__ o, int M){
    int i = blockIdx.x*256 + threadIdx.x;
    if (i < M) o[i] = make_float4(s[i*3+0], s[i*3+1], s[i*3+2], 0.f);
}

// Wt2[((k*8 + f)*64 + lane)*8 + j] = bf16( W[k][ks*32 + (lane>>4)*8 + j][ot*16 + (lane&15)] ), f = ot*2+ks
__global__ void pack_wt2(const float* __restrict__ W, unsigned short* __restrict__ Wt2){
    int tid = blockIdx.x*256 + threadIdx.x;
    if (tid >= KP*8*64) return;
    int lane = tid & 63;
    int f  = (tid>>6) & 7;
    int k  = tid >> 9;
    int ot = f>>1, ks = f&1, g = lane>>4;
    unsigned r[8];
#pragma unroll
    for (int j=0;j<8;++j)
        r[j] = f2bf(W[(size_t)k*4096 + (size_t)(ks*32 + g*8 + j)*64 + ot*16 + (lane&15)]);
    uint4 v; v.x=r[0]|(r[1]<<16); v.y=r[2]|(r[3]<<16); v.z=r[4]|(r[5]<<16); v.w=r[6]|(r[7]<<16);
    *(uint4*)&Wt2[(size_t)tid*8] = v;
}

// prep: sp4 pack + Wt2 pack in one launch
__global__ __launch_bounds__(256)
void kp_prep2(const float* __restrict__ s, const float* __restrict__ W,
              float4* __restrict__ o, unsigned short* __restrict__ Wt2, int M)
{
    int tid = blockIdx.x*256 + threadIdx.x;
    if (tid < M) o[tid] = make_float4(s[tid*3+0], s[tid*3+1], s[tid*3+2], 0.f);
    if (tid < KP*8*64){
        int lane = tid & 63;
        int f  = (tid>>6) & 7;
        int kk = tid >> 9;
        int ot = f>>1, ks = f&1, gg = lane>>4;
        unsigned r[8];
#pragma unroll
        for (int j=0;j<8;++j)
            r[j] = f2bf(W[(size_t)kk*4096 + (size_t)(ks*32 + gg*8 + j)*64 + ot*16 + (lane&15)]);
        uint4 v; v.x=r[0]|(r[1]<<16); v.y=r[2]|(r[3]<<16); v.z=r[4]|(r[5]<<16); v.w=r[6]|(r[7]<<16);
        *(uint4*)&Wt2[(size_t)tid*8] = v;
    }
}

__device__ __forceinline__ void loadB(const unsigned short* __restrict__ Wt2, int k, int lane,
                                      bf16x8 (&b)[8]){
    const unsigned short* base = Wt2 + ((size_t)(k*8)*64 + lane)*8;
#pragma unroll
    for (int f=0;f<8;++f) b[f] = *(const bf16x8*)(base + f*512);
}
__device__ __forceinline__ bf16x8 ldBf(const unsigned short* __restrict__ Wt2, int k, int f, int lane){
    return *(const bf16x8*)(Wt2 + ((size_t)(k*8 + f)*64 + lane)*8);
}
__device__ __forceinline__ void loadB_w(const float* __restrict__ W, int k, int lane, int g,
                                        bf16x8 (&b)[8]){
#pragma unroll
    for (int f=0;f<8;++f){
        int ot=f>>1, ks=f&1;
        union{unsigned u[4]; bf16x8 v;} bb;
#pragma unroll
        for (int jj=0;jj<4;++jj){
            unsigned l0=f2bf(W[(size_t)k*4096 + (size_t)(ks*32+g*8+2*jj)*64   + ot*16+(lane&15)]);
            unsigned l1=f2bf(W[(size_t)k*4096 + (size_t)(ks*32+g*8+2*jj+1)*64 + ot*16+(lane&15)]);
            bb.u[jj]=l0|(l1<<16);
        }
        b[f]=bb.v;
    }
}

// ====================== FUSED KERNEL =======================================
// Block = 64 queries (2048 pairs), 256 threads (4 waves), ~36 KB LDS
// -> 4 blocks/CU; 625 blocks ~ all co-resident. Phases per block:
//   A) scan 2048 pairs, compact survivors into LDS (mean 54, cap 128)
//   B) per 64-entry tile: stage bf16 rows (XOR swizzle) + w-table, MFMA over
//      all 27 kernel points (wave wv owns output cols [wv*16,wv*16+16)),
//      flush to LDS outacc via LDS atomics (cross-tile same-query safe)
//   C) write full out rows for the block's 64 queries (no global zero pass,
//      no global atomics)
__global__ __launch_bounds__(256,4)
void kpconv_fused(const float* __restrict__ q_pts, const int* __restrict__ inds,
                  const float* __restrict__ x, const float* __restrict__ kpts,
                  const float4* __restrict__ sp4, const unsigned short* __restrict__ Wt2,
                  float* __restrict__ out, int N, int M)
{
    __shared__ unsigned short rows[64*CIN];            // 8 KB, XOR-swizzled bf16
    __shared__ __align__(16) float wlds[KP*64];        // 6.75 KB
    __shared__ __align__(16) float outacc[QB2*OSTR2];  // 17.4 KB
    __shared__ float qls[QB2*3];
    __shared__ float bx[CAP2], by[CAP2], bz[CAP2];
    __shared__ __align__(16) int bq[CAP2];
    __shared__ int bixs[CAP2];
    __shared__ int cnt;

    const int t    = threadIdx.x;
    const int lane = t & 63;
    const int wv   = t >> 6;        // wave owns output cols [wv*16, wv*16+16)
    const int g    = lane >> 4;
    const int r15  = lane & 15;
    const int nq0  = blockIdx.x * QB2;
    const int NP   = N*HN;

    for (int j=t; j<QB2*OSTR2; j+=256) outacc[j]=0.f;
    for (int j=t; j<QB2*3;    j+=256){ int gi=nq0*3+j; qls[j]=(gi<N*3)? q_pts[gi]:0.f; }
    if (t < CAP2) bq[t]=0;
    if (t==0) cnt=0;
    __syncthreads();

    // ---- phase A: scan 2048 pairs (8 per thread, unrolled for MLP) ----
#pragma unroll
    for (int jj=0; jj<8; ++jj){
        int pl   = jj*256 + t;
        int pair = nq0*HN + pl;
        if (pair < NP){
            int idx = inds[pair];
            if ((unsigned)idx < (unsigned)M){       // idx==M is shadow point
                int q = pl >> 5;
                float4 s4 = sp4[idx];
                float px=s4.x-qls[q*3], py=s4.y-qls[q*3+1], pz=s4.z-qls[q*3+2];
                if (px*px+py*py+pz*pz <= CUT2){
                    int sl = atomicAdd(&cnt, 1);
                    if (sl < CAP2){ bx[sl]=px; by[sl]=py; bz[sl]=pz; bq[sl]=q; bixs[sl]=idx; }
                }
            }
        }
    }
    __syncthreads();
    const int total = cnt;

    auto processTile = [&](int base, int cc){
        // stage 64 feature rows (f32 -> bf16, swizzled); zero-pad past cc
        for (int it=t; it<64*8; it+=256){
            int rl=it>>3, c8=it&7, e=base+rl;
            uint4 v; v.x=0u; v.y=0u; v.z=0u; v.w=0u;
            if (e < cc){
                int ix = bixs[e];
                const float4* xr = (const float4*)(x + (size_t)ix*CIN);
                float4 f0=xr[c8*2], f1=xr[c8*2+1];
                v.x=f2bf(f0.x)|(f2bf(f0.y)<<16); v.y=f2bf(f0.z)|(f2bf(f0.w)<<16);
                v.z=f2bf(f1.x)|(f2bf(f1.y)<<16); v.w=f2bf(f1.z)|(f2bf(f1.w)<<16);
            }
            int ba = rl*128 + ((c8*16)^((rl&7)<<4));
            *(uint4*)((char*)rows+ba) = v;
        }
        // w table: w[k][row]
        for (int i=t; i<KP*64; i+=256){
            int k=i>>6, row=i&63, e=base+row;
            float w=0.f;
            if (e < cc){
                float dx=bx[e]-kpts[k*3+0];
                float dy=by[e]-kpts[k*3+1];
                float dz=bz[e]-kpts[k*3+2];
                w = fmaxf(1.f - sqrtf(dx*dx+dy*dy+dz*dz)*INV_EXT, 0.f);
            }
            wlds[i]=w;
        }
        __syncthreads();

        const char* rb = (const char*)rows;
        bf16x8 A0[4], A1[4];
#pragma unroll
        for (int rt=0; rt<4; ++rt){
            int row = rt*16 + r15;
            A0[rt] = *(const bf16x8*)(rb + row*128 + (( g*16)    ^((row&7)<<4)));
            A1[rt] = *(const bf16x8*)(rb + row*128 + ((64+g*16)  ^((row&7)<<4)));
        }
        f32x4 acc[4];
#pragma unroll
        for (int rt=0; rt<4; ++rt){ acc[rt][0]=0.f; acc[rt][1]=0.f; acc[rt][2]=0.f; acc[rt][3]=0.f; }

        const int f0 = wv*2, f1 = wv*2+1;
        bf16x8 Bc0 = ldBf(Wt2, 0, f0, lane);
        bf16x8 Bc1 = ldBf(Wt2, 0, f1, lane);
#pragma unroll 1
        for (int k=0; k<KP; ++k){
            int kn = (k+1 < KP) ? (k+1) : k;
            bf16x8 Bn0 = ldBf(Wt2, kn, f0, lane);
            bf16x8 Bn1 = ldBf(Wt2, kn, f1, lane);
            const float* wk = &wlds[k*64];
#pragma unroll
            for (int rt=0; rt<4; ++rt){
                f32x4 w4 = *(const f32x4*)(wk + rt*16 + g*4);
                bool act = (w4[0]>0.f)|(w4[1]>0.f)|(w4[2]>0.f)|(w4[3]>0.f);
                if (__any(act)){
                    f32x4 c; c[0]=0.f; c[1]=0.f; c[2]=0.f; c[3]=0.f;
                    c = __builtin_amdgcn_mfma_f32_16x16x32_bf16(A0[rt], Bc0, c, 0,0,0);
                    c = __builtin_amdgcn_mfma_f32_16x16x32_bf16(A1[rt], Bc1, c, 0,0,0);
                    acc[rt][0] += w4[0]*c[0];
                    acc[rt][1] += w4[1]*c[1];
                    acc[rt][2] += w4[2]*c[2];
                    acc[rt][3] += w4[3]*c[3];
                }
            }
            Bc0 = Bn0; Bc1 = Bn1;
        }
        // flush to LDS outacc (LDS atomics: same query may recur across rows/tiles)
#pragma unroll
        for (int rt=0; rt<4; ++rt){
            int4 q4 = *(const int4*)&bq[base + rt*16 + g*4];
#pragma unroll
            for (int rr=0; rr<4; ++rr){
                float val = acc[rt][rr];
                int qv = (rr==0)? q4.x : (rr==1)? q4.y : (rr==2)? q4.z : q4.w;
                if (val != 0.f)
                    atomicAdd(&outacc[qv*OSTR2 + wv*16 + r15], val);
            }
        }
        __syncthreads();    // rows/wlds free for next tile; flush visible
    };

    if (total <= CAP2){
        int nt = (total + 63) >> 6;
        for (int tile=0; tile<nt; ++tile) processTile(tile*64, total);
    } else {
        // exact fallback: re-scan in windows of 64 pairs (<=64 survivors <= CAP2)
        for (int w=0; w<(QB2*HN)/64; ++w){
            __syncthreads();
            if (t==0) cnt=0;
            __syncthreads();
            if (t < 64){
                int pl = w*64 + t, pair = nq0*HN + pl;
                if (pair < NP){
                    int idx = inds[pair];
                    if ((unsigned)idx < (unsigned)M){
                        int q = pl >> 5;
                        float4 s4 = sp4[idx];
                        float px=s4.x-qls[q*3], py=s4.y-qls[q*3+1], pz=s4.z-qls[q*3+2];
                        if (px*px+py*py+pz*pz <= CUT2){
                            int sl = atomicAdd(&cnt, 1);
                            bx[sl]=px; by[sl]=py; bz[sl]=pz; bq[sl]=q; bixs[sl]=idx;
                        }
                    }
                }
            }
            __syncthreads();
            if (cnt > 0) processTile(0, cnt);
        }
    }
    __syncthreads();

    // ---- phase C: write full rows (covers zero-survivor queries too) ----
    for (int j=t; j<QB2*16; j+=256){
        int q=j>>4, o4=j&15, n=nq0+q;
        if (n < N)
            ((float4*)out)[(size_t)n*16 + o4] = *(const float4*)&outacc[q*OSTR2 + o4*4];
    }
}

// ====================== OLD PATH (fallback, no workspace) ==================

__global__ __launch_bounds__(NTB)
void kpconv6(const float* __restrict__ q_pts, const float* __restrict__ s_pts,
             const int* __restrict__ inds, const float* __restrict__ x,
             const float* __restrict__ W, const float* __restrict__ kpts,
             const float4* __restrict__ sp4, const unsigned short* __restrict__ Wt2,
             int use_ws, float* __restrict__ out, int N, int M)
{
    __shared__ float qls[QB*3];
    __shared__ float posx[CAPB], posy[CAPB], posz[CAPB];
    __shared__ int   eqb[CAPB], eidxb[CAPB];
    __shared__ unsigned short rows[CAPB*CIN];
    __shared__ float outacc[QB*OSTR];
    __shared__ int   cnt;

    const int t    = threadIdx.x;
    const int lane = t & 63;
    const int wv   = t >> 6;
    const int g    = lane >> 4;
    const int r15  = lane & 15;
    const int nq0  = blockIdx.x * QB;

    const int k0 = wv, k1 = wv + 16;
    const bool has2 = (k1 < KP);

    bf16x8 B0[8], B1[8];
    if (use_ws){
        loadB(Wt2, k0, lane, B0);
        loadB(Wt2, has2 ? k1 : k0, lane, B1);
    } else {
        loadB_w(W, k0, lane, g, B0);
        loadB_w(W, has2 ? k1 : k0, lane, g, B1);
    }
    const float k0x=kpts[k0*3+0], k0y=kpts[k0*3+1], k0z=kpts[k0*3+2];
    float k1x=0.f,k1y=0.f,k1z=0.f;
    if (has2){ k1x=kpts[k1*3+0]; k1y=kpts[k1*3+1]; k1z=kpts[k1*3+2]; }

    for (int j=t; j<QB*OSTR; j+=NTB) outacc[j]=0.f;
    for (int j=t; j<QB*3;   j+=NTB){ int gi=nq0*3+j; qls[j]=(gi<N*3)? q_pts[gi]:0.f; }
    if (t==0) cnt=0;
    __syncthreads();

    auto process = [&](int cc){
        if (cc<=0) return;
        const int ntile=(cc+15)>>4, nrow=ntile*16;
        for (int j=cc+t; j<nrow; j+=NTB){ posx[j]=1e9f; posy[j]=1e9f; posz[j]=1e9f; eqb[j]=0; }
        for (int it=t; it<nrow*8; it+=NTB){
            int e=it>>3, c8=it&7;
            uint4 v; v.x=0u; v.y=0u; v.z=0u; v.w=0u;
            if (e<cc){
                const float4* xr=(const float4*)(x+(size_t)eidxb[e]*CIN);
                float4 f0=xr[c8*2], f1=xr[c8*2+1];
                v.x=f2bf(f0.x)|(f2bf(f0.y)<<16); v.y=f2bf(f0.z)|(f2bf(f0.w)<<16);
                v.z=f2bf(f1.x)|(f2bf(f1.y)<<16); v.w=f2bf(f1.z)|(f2bf(f1.w)<<16);
            }
            int ba=e*128+((c8*16)^((e&7)<<4));
            *(uint4*)((char*)rows+ba)=v;
        }
        __syncthreads();
        for (int tile=0; tile<ntile; ++tile){
            const char* rb=(const char*)rows;
            int row=tile*16+r15;
            bf16x8 a0=*(const bf16x8*)(rb+row*128+((g*16)    ^((row&7)<<4)));
            bf16x8 a1=*(const bf16x8*)(rb+row*128+((64+g*16) ^((row&7)<<4)));
            int rbase=tile*16+g*4;
            float w0[4], w1[4]; int qq[4];
#pragma unroll
            for (int r=0;r<4;++r){
                float sx=posx[rbase+r], sy=posy[rbase+r], sz=posz[rbase+r];
                qq[r]=eqb[rbase+r];
                float dx=sx-k0x, dy=sy-k0y, dz=sz-k0z;
                w0[r]=fmaxf(1.f-sqrtf(dx*dx+dy*dy+dz*dz)*INV_EXT,0.f);
                float ex=sx-k1x, ey=sy-k1y, ez=sz-k1z;
                float w1r=fmaxf(1.f-sqrtf(ex*ex+ey*ey+ez*ez)*INV_EXT,0.f);
                w1[r]=has2? w1r : 0.f;
            }
#pragma unroll
            for (int ot=0;ot<4;++ot){
                f32x4 c={0.f,0.f,0.f,0.f};
                c=__builtin_amdgcn_mfma_f32_16x16x32_bf16(a0,B0[2*ot],c,0,0,0);
                c=__builtin_amdgcn_mfma_f32_16x16x32_bf16(a1,B0[2*ot+1],c,0,0,0);
                f32x4 d={0.f,0.f,0.f,0.f};
                if (has2){
                    d=__builtin_amdgcn_mfma_f32_16x16x32_bf16(a0,B1[2*ot],d,0,0,0);
                    d=__builtin_amdgcn_mfma_f32_16x16x32_bf16(a1,B1[2*ot+1],d,0,0,0);
                }
#pragma unroll
                for (int r=0;r<4;++r){
                    float val=w0[r]*c[r]+w1[r]*d[r];
                    if (val!=0.f) atomicAdd(&outacc[qq[r]*OSTR+ot*16+r15], val);
                }
            }
        }
        __syncthreads();
    };

    for (int it=t; it<QB*HN; it+=NTB){
        int q=it>>5, h=it&31, n=nq0+q;
        bool inr=false; int idx=0; float px=0.f,py=0.f,pz=0.f;
        if (n<N){
            idx=inds[(size_t)n*HN+h];
            if ((unsigned)idx<(unsigned)M){
                float sx,sy,sz;
                if (use_ws){ float4 s4=sp4[idx]; sx=s4.x; sy=s4.y; sz=s4.z; }
                else { sx=s_pts[idx*3]; sy=s_pts[idx*3+1]; sz=s_pts[idx*3+2]; }
                px=sx-qls[q*3]; py=sy-qls[q*3+1]; pz=sz-qls[q*3+2];
                inr=(px*px+py*py+pz*pz)<=CUT2;
            }
        }
        if (inr){
            int sl=atomicAdd(&cnt,1);
            if (sl<CAPB){ eqb[sl]=q; eidxb[sl]=idx; posx[sl]=px; posy[sl]=py; posz[sl]=pz; }
        }
    }
    __syncthreads();
    const int total=cnt;

    if (total<=CAPB){
        process(total);
    } else {
        for (int w=0; w<(QB*HN)/64; ++w){
            __syncthreads();
            if (t==0) cnt=0;
            __syncthreads();
            if (t<64){
                int pair=w*64+t;
                int q=pair>>5, h=pair&31, n=nq0+q;
                if (n<N){
                    int idx=inds[(size_t)n*HN+h];
                    if ((unsigned)idx<(unsigned)M){
                        float sx,sy,sz;
                        if (use_ws){ float4 s4=sp4[idx]; sx=s4.x; sy=s4.y; sz=s4.z; }
                        else { sx=s_pts[idx*3]; sy=s_pts[idx*3+1]; sz=s_pts[idx*3+2]; }
                        float px=sx-qls[q*3], py=sy-qls[q*3+1], pz=sz-qls[q*3+2];
                        if (px*px+py*py+pz*pz<=CUT2){
                            int sl=atomicAdd(&cnt,1);
                            eqb[sl]=q; eidxb[sl]=idx; posx[sl]=px; posy[sl]=py; posz[sl]=pz;
                        }
                    }
                }
            }
            __syncthreads();
            process(cnt);
        }
    }
    __syncthreads();

    for (int j=t; j<QB*CIN; j+=NTB){
        int q=j>>6, o=j&63, n=nq0+q;
        if (n<N) out[(size_t)n*CIN+o]=outacc[q*OSTR+o];
    }
}

extern "C" void kernel_launch(void* const* d_in, const int* in_sizes, int n_in,
                              void* d_out, int out_size, void* d_ws, size_t ws_size,
                              hipStream_t stream)
{
    const float* q_pts=(const float*)d_in[0];
    const float* s_pts=(const float*)d_in[1];
    const int*   inds =(const int*)d_in[2];
    const float* x    =(const float*)d_in[3];
    const float* W    =(const float*)d_in[4];
    const float* kpts =(const float*)d_in[5];
    float* outp=(float*)d_out;
    int N=in_sizes[0]/3;
    int M=in_sizes[1]/3;

    char* wsb=(char*)d_ws;
    float4* sp4=(float4*)wsb;
    unsigned short* Wt2=(unsigned short*)(wsb + (size_t)M*16);

    const size_t WT2B = (size_t)KP*8*64*8*2;            // 221184
    size_t need = (size_t)M*16 + WT2B;

    if (ws_size >= need){
        int prepN = (M > KP*8*64) ? M : KP*8*64;
        hipLaunchKernelGGL(kp_prep2, dim3((prepN+255)/256), dim3(256), 0, stream,
                           s_pts, W, sp4, Wt2, M);
        int nblocks = (N + QB2 - 1) / QB2;
        hipLaunchKernelGGL(kpconv_fused, dim3(nblocks), dim3(256), 0, stream,
                           q_pts, inds, x, kpts, sp4, Wt2, outp, N, M);
        return;
    }

    // fallback: no workspace
    hipLaunchKernelGGL(kpconv6, dim3((N+QB-1)/QB), dim3(NTB), 0, stream,
                       q_pts, s_pts, inds, x, W, kpts, sp4, Wt2, 0, outp, N, M);
}

// Round 4
// 41.121 us; speedup vs baseline: 1.0900x; 1.0900x over previous
//
#include <hip/hip_runtime.h>

typedef short bf16x8 __attribute__((ext_vector_type(8)));
typedef float f32x4  __attribute__((ext_vector_type(4)));

#define HN    32
#define CIN   64
#define KP    27
#define QB    64          // queries per block (old fallback path)
#define CAPB  96          // entry slots per block (old fallback path)
#define NTB   1024        // 16 waves (old fallback path)
#define OSTR  65          // outacc stride (old fallback path)

// fused path
#define QB2   32          // queries per fused block (1024 pairs)
#define CAP2  64          // survivor capacity (mean ~27, sigma ~5 -> +7 sigma)
#define OSTR2 68          // outacc stride: 16B-aligned float4 rows, bank-skewed

#define INV_EXT 1.1547005383792517f   // 1/0.8660254
#define CUT2    3.4821f               // (1+0.8660254)^2 padded (extras get w=0)

__device__ __forceinline__ unsigned f2bf(float f){
    union{float fv;unsigned u;}v; v.fv=f;
    unsigned u=v.u;
    u += 0x7fffu + ((u>>16)&1u);      // RNE
    return u>>16;
}

// ---------------- pack kernels -------------------------------------------
__global__ void pack_spts(const float* __restrict__ s, float4* __restrict__ o, int M){
    int i = blockIdx.x*256 + threadIdx.x;
    if (i < M) o[i] = make_float4(s[i*3+0], s[i*3+1], s[i*3+2], 0.f);
}

// Wt2[((k*8 + f)*64 + lane)*8 + j] = bf16( W[k][ks*32 + (lane>>4)*8 + j][ot*16 + (lane&15)] ), f = ot*2+ks
__global__ void pack_wt2(const float* __restrict__ W, unsigned short* __restrict__ Wt2){
    int tid = blockIdx.x*256 + threadIdx.x;
    if (tid >= KP*8*64) return;
    int lane = tid & 63;
    int f  = (tid>>6) & 7;
    int k  = tid >> 9;
    int ot = f>>1, ks = f&1, g = lane>>4;
    unsigned r[8];
#pragma unroll
    for (int j=0;j<8;++j)
        r[j] = f2bf(W[(size_t)k*4096 + (size_t)(ks*32 + g*8 + j)*64 + ot*16 + (lane&15)]);
    uint4 v; v.x=r[0]|(r[1]<<16); v.y=r[2]|(r[3]<<16); v.z=r[4]|(r[5]<<16); v.w=r[6]|(r[7]<<16);
    *(uint4*)&Wt2[(size_t)tid*8] = v;
}

// prep: sp4 pack + Wt2 pack in one launch
__global__ __launch_bounds__(256)
void kp_prep2(const float* __restrict__ s, const float* __restrict__ W,
              float4* __restrict__ o, unsigned short* __restrict__ Wt2, int M)
{
    int tid = blockIdx.x*256 + threadIdx.x;
    if (tid < M) o[tid] = make_float4(s[tid*3+0], s[tid*3+1], s[tid*3+2], 0.f);
    if (tid < KP*8*64){
        int lane = tid & 63;
        int f  = (tid>>6) & 7;
        int kk = tid >> 9;
        int ot = f>>1, ks = f&1, gg = lane>>4;
        unsigned r[8];
#pragma unroll
        for (int j=0;j<8;++j)
            r[j] = f2bf(W[(size_t)kk*4096 + (size_t)(ks*32 + gg*8 + j)*64 + ot*16 + (lane&15)]);
        uint4 v; v.x=r[0]|(r[1]<<16); v.y=r[2]|(r[3]<<16); v.z=r[4]|(r[5]<<16); v.w=r[6]|(r[7]<<16);
        *(uint4*)&Wt2[(size_t)tid*8] = v;
    }
}

__device__ __forceinline__ void loadB(const unsigned short* __restrict__ Wt2, int k, int lane,
                                      bf16x8 (&b)[8]){
    const unsigned short* base = Wt2 + ((size_t)(k*8)*64 + lane)*8;
#pragma unroll
    for (int f=0;f<8;++f) b[f] = *(const bf16x8*)(base + f*512);
}
__device__ __forceinline__ bf16x8 ldBf(const unsigned short* __restrict__ Wt2, int k, int f, int lane){
    return *(const bf16x8*)(Wt2 + ((size_t)(k*8 + f)*64 + lane)*8);
}
__device__ __forceinline__ void loadB_w(const float* __restrict__ W, int k, int lane, int g,
                                        bf16x8 (&b)[8]){
#pragma unroll
    for (int f=0;f<8;++f){
        int ot=f>>1, ks=f&1;
        union{unsigned u[4]; bf16x8 v;} bb;
#pragma unroll
        for (int jj=0;jj<4;++jj){
            unsigned l0=f2bf(W[(size_t)k*4096 + (size_t)(ks*32+g*8+2*jj)*64   + ot*16+(lane&15)]);
            unsigned l1=f2bf(W[(size_t)k*4096 + (size_t)(ks*32+g*8+2*jj+1)*64 + ot*16+(lane&15)]);
            bb.u[jj]=l0|(l1<<16);
        }
        b[f]=bb.v;
    }
}

// ====================== FUSED KERNEL =======================================
// Block = 32 queries (1024 pairs), 256 threads (4 waves), ~25.5 KB LDS
// -> 6 blocks/CU LDS-capacity; grid 1250 blocks ~ 4.9/CU resident.
// Phases: A) scan+compact to LDS (mean ~27, cap 64);
//         B) single 64-row tile: stage bf16 rows (XOR swizzle) + w-table,
//            27-kpoint MFMA loop (wave wv owns out cols [wv*16,wv*16+16)),
//            per-16-row-group guards skip padding; flush via LDS atomics;
//         C) write full rows (no global zero pass, no global atomics).
__global__ __launch_bounds__(256,5)
void kpconv_fused(const float* __restrict__ q_pts, const int* __restrict__ inds,
                  const float* __restrict__ x, const float* __restrict__ kpts,
                  const float4* __restrict__ sp4, const unsigned short* __restrict__ Wt2,
                  float* __restrict__ out, int N, int M)
{
    __shared__ unsigned short rows[64*CIN];            // 8 KB, XOR-swizzled bf16
    __shared__ __align__(16) float wlds[KP*64];        // 6.75 KB
    __shared__ __align__(16) float outacc[QB2*OSTR2];  // 8.7 KB
    __shared__ float qls[QB2*3];
    __shared__ float bx[CAP2], by[CAP2], bz[CAP2];
    __shared__ __align__(16) int bq[CAP2];
    __shared__ int bixs[CAP2];
    __shared__ int cnt;

    const int t    = threadIdx.x;
    const int lane = t & 63;
    const int wv   = t >> 6;        // wave owns output cols [wv*16, wv*16+16)
    const int g    = lane >> 4;
    const int r15  = lane & 15;
    const int nq0  = blockIdx.x * QB2;
    const int NP   = N*HN;

    for (int j=t; j<QB2*OSTR2; j+=256) outacc[j]=0.f;
    for (int j=t; j<QB2*3;    j+=256){ int gi=nq0*3+j; qls[j]=(gi<N*3)? q_pts[gi]:0.f; }
    if (t < CAP2) bq[t]=0;
    if (t==0) cnt=0;
    __syncthreads();

    // ---- phase A: scan 1024 pairs (4 per thread, unrolled for MLP) ----
#pragma unroll
    for (int jj=0; jj<4; ++jj){
        int pl   = jj*256 + t;
        int pair = nq0*HN + pl;
        if (pair < NP){
            int idx = inds[pair];
            if ((unsigned)idx < (unsigned)M){       // idx==M is shadow point
                int q = pl >> 5;
                float4 s4 = sp4[idx];
                float px=s4.x-qls[q*3], py=s4.y-qls[q*3+1], pz=s4.z-qls[q*3+2];
                if (px*px+py*py+pz*pz <= CUT2){
                    int sl = atomicAdd(&cnt, 1);
                    if (sl < CAP2){ bx[sl]=px; by[sl]=py; bz[sl]=pz; bq[sl]=q; bixs[sl]=idx; }
                }
            }
        }
    }
    __syncthreads();
    const int total = cnt;

    auto processTile = [&](int cc){
        const int nrow = (cc + 15) & ~15;          // <=64
        // B-frag prefetch first: L2 latency hides under staging/w-table
        const int f0 = wv*2, f1 = wv*2+1;
        bf16x8 Bc0 = ldBf(Wt2, 0, f0, lane);
        bf16x8 Bc1 = ldBf(Wt2, 0, f1, lane);
        // stage nrow feature rows (f32 -> bf16, swizzled); zero-pad past cc
        for (int it=t; it<nrow*8; it+=256){
            int rl=it>>3, c8=it&7;
            uint4 v; v.x=0u; v.y=0u; v.z=0u; v.w=0u;
            if (rl < cc){
                int ix = bixs[rl];
                const float4* xr = (const float4*)(x + (size_t)ix*CIN);
                float4 fr0=xr[c8*2], fr1=xr[c8*2+1];
                v.x=f2bf(fr0.x)|(f2bf(fr0.y)<<16); v.y=f2bf(fr0.z)|(f2bf(fr0.w)<<16);
                v.z=f2bf(fr1.x)|(f2bf(fr1.y)<<16); v.w=f2bf(fr1.z)|(f2bf(fr1.w)<<16);
            }
            int ba = rl*128 + ((c8*16)^((rl&7)<<4));
            *(uint4*)((char*)rows+ba) = v;
        }
        // w table: w[k][row] for row < nrow (rows in [cc,nrow) get 0)
        for (int i=t; i<KP*64; i+=256){
            int row = i&63;
            if (row >= nrow) continue;
            int k = i>>6;
            float w=0.f;
            if (row < cc){
                float dx=bx[row]-kpts[k*3+0];
                float dy=by[row]-kpts[k*3+1];
                float dz=bz[row]-kpts[k*3+2];
                w = fmaxf(1.f - sqrtf(dx*dx+dy*dy+dz*dz)*INV_EXT, 0.f);
            }
            wlds[i]=w;
        }
        __syncthreads();

        const char* rb = (const char*)rows;
        bf16x8 A0[4], A1[4];
#pragma unroll
        for (int rt=0; rt<4; ++rt){
            if (rt*16 >= cc) continue;
            int row = rt*16 + r15;
            A0[rt] = *(const bf16x8*)(rb + row*128 + (( g*16)    ^((row&7)<<4)));
            A1[rt] = *(const bf16x8*)(rb + row*128 + ((64+g*16)  ^((row&7)<<4)));
        }
        f32x4 acc[4];
#pragma unroll
        for (int rt=0; rt<4; ++rt){ acc[rt][0]=0.f; acc[rt][1]=0.f; acc[rt][2]=0.f; acc[rt][3]=0.f; }

#pragma unroll 1
        for (int k=0; k<KP; ++k){
            int kn = (k+1 < KP) ? (k+1) : k;
            bf16x8 Bn0 = ldBf(Wt2, kn, f0, lane);
            bf16x8 Bn1 = ldBf(Wt2, kn, f1, lane);
            const float* wk = &wlds[k*64];
#pragma unroll
            for (int rt=0; rt<4; ++rt){
                if (rt*16 >= cc) continue;
                f32x4 w4 = *(const f32x4*)(wk + rt*16 + g*4);
                bool act = (w4[0]>0.f)|(w4[1]>0.f)|(w4[2]>0.f)|(w4[3]>0.f);
                if (__any(act)){
                    f32x4 c; c[0]=0.f; c[1]=0.f; c[2]=0.f; c[3]=0.f;
                    c = __builtin_amdgcn_mfma_f32_16x16x32_bf16(A0[rt], Bc0, c, 0,0,0);
                    c = __builtin_amdgcn_mfma_f32_16x16x32_bf16(A1[rt], Bc1, c, 0,0,0);
                    acc[rt][0] += w4[0]*c[0];
                    acc[rt][1] += w4[1]*c[1];
                    acc[rt][2] += w4[2]*c[2];
                    acc[rt][3] += w4[3]*c[3];
                }
            }
            Bc0 = Bn0; Bc1 = Bn1;
        }
        // flush to LDS outacc (LDS atomics: same query may recur across rows)
#pragma unroll
        for (int rt=0; rt<4; ++rt){
            if (rt*16 >= cc) continue;
            int4 q4 = *(const int4*)&bq[rt*16 + g*4];
#pragma unroll
            for (int rr=0; rr<4; ++rr){
                float val = acc[rt][rr];
                int qv = (rr==0)? q4.x : (rr==1)? q4.y : (rr==2)? q4.z : q4.w;
                if (val != 0.f)
                    atomicAdd(&outacc[qv*OSTR2 + wv*16 + r15], val);
            }
        }
        __syncthreads();    // flush visible; rows/wlds free for reuse
    };

    if (total <= CAP2){
        if (total > 0) processTile(total);
    } else {
        // exact fallback: re-scan in windows of 64 pairs (<=64 survivors <= CAP2)
        for (int w=0; w<(QB2*HN)/64; ++w){
            __syncthreads();
            if (t==0) cnt=0;
            __syncthreads();
            if (t < 64){
                int pl = w*64 + t, pair = nq0*HN + pl;
                if (pair < NP){
                    int idx = inds[pair];
                    if ((unsigned)idx < (unsigned)M){
                        int q = pl >> 5;
                        float4 s4 = sp4[idx];
                        float px=s4.x-qls[q*3], py=s4.y-qls[q*3+1], pz=s4.z-qls[q*3+2];
                        if (px*px+py*py+pz*pz <= CUT2){
                            int sl = atomicAdd(&cnt, 1);
                            bx[sl]=px; by[sl]=py; bz[sl]=pz; bq[sl]=q; bixs[sl]=idx;
                        }
                    }
                }
            }
            __syncthreads();
            if (cnt > 0) processTile(cnt);
        }
    }
    __syncthreads();

    // ---- phase C: write full rows (covers zero-survivor queries too) ----
    for (int j=t; j<QB2*16; j+=256){
        int q=j>>4, o4=j&15, n=nq0+q;
        if (n < N)
            ((float4*)out)[(size_t)n*16 + o4] = *(const float4*)&outacc[q*OSTR2 + o4*4];
    }
}

// ====================== OLD PATH (fallback, no workspace) ==================

__global__ __launch_bounds__(NTB)
void kpconv6(const float* __restrict__ q_pts, const float* __restrict__ s_pts,
             const int* __restrict__ inds, const float* __restrict__ x,
             const float* __restrict__ W, const float* __restrict__ kpts,
             const float4* __restrict__ sp4, const unsigned short* __restrict__ Wt2,
             int use_ws, float* __restrict__ out, int N, int M)
{
    __shared__ float qls[QB*3];
    __shared__ float posx[CAPB], posy[CAPB], posz[CAPB];
    __shared__ int   eqb[CAPB], eidxb[CAPB];
    __shared__ unsigned short rows[CAPB*CIN];
    __shared__ float outacc[QB*OSTR];
    __shared__ int   cnt;

    const int t    = threadIdx.x;
    const int lane = t & 63;
    const int wv   = t >> 6;
    const int g    = lane >> 4;
    const int r15  = lane & 15;
    const int nq0  = blockIdx.x * QB;

    const int k0 = wv, k1 = wv + 16;
    const bool has2 = (k1 < KP);

    bf16x8 B0[8], B1[8];
    if (use_ws){
        loadB(Wt2, k0, lane, B0);
        loadB(Wt2, has2 ? k1 : k0, lane, B1);
    } else {
        loadB_w(W, k0, lane, g, B0);
        loadB_w(W, has2 ? k1 : k0, lane, g, B1);
    }
    const float k0x=kpts[k0*3+0], k0y=kpts[k0*3+1], k0z=kpts[k0*3+2];
    float k1x=0.f,k1y=0.f,k1z=0.f;
    if (has2){ k1x=kpts[k1*3+0]; k1y=kpts[k1*3+1]; k1z=kpts[k1*3+2]; }

    for (int j=t; j<QB*OSTR; j+=NTB) outacc[j]=0.f;
    for (int j=t; j<QB*3;   j+=NTB){ int gi=nq0*3+j; qls[j]=(gi<N*3)? q_pts[gi]:0.f; }
    if (t==0) cnt=0;
    __syncthreads();

    auto process = [&](int cc){
        if (cc<=0) return;
        const int ntile=(cc+15)>>4, nrow=ntile*16;
        for (int j=cc+t; j<nrow; j+=NTB){ posx[j]=1e9f; posy[j]=1e9f; posz[j]=1e9f; eqb[j]=0; }
        for (int it=t; it<nrow*8; it+=NTB){
            int e=it>>3, c8=it&7;
            uint4 v; v.x=0u; v.y=0u; v.z=0u; v.w=0u;
            if (e<cc){
                const float4* xr=(const float4*)(x+(size_t)eidxb[e]*CIN);
                float4 f0=xr[c8*2], f1=xr[c8*2+1];
                v.x=f2bf(f0.x)|(f2bf(f0.y)<<16); v.y=f2bf(f0.z)|(f2bf(f0.w)<<16);
                v.z=f2bf(f1.x)|(f2bf(f1.y)<<16); v.w=f2bf(f1.z)|(f2bf(f1.w)<<16);
            }
            int ba=e*128+((c8*16)^((e&7)<<4));
            *(uint4*)((char*)rows+ba)=v;
        }
        __syncthreads();
        for (int tile=0; tile<ntile; ++tile){
            const char* rb=(const char*)rows;
            int row=tile*16+r15;
            bf16x8 a0=*(const bf16x8*)(rb+row*128+((g*16)    ^((row&7)<<4)));
            bf16x8 a1=*(const bf16x8*)(rb+row*128+((64+g*16) ^((row&7)<<4)));
            int rbase=tile*16+g*4;
            float w0[4], w1[4]; int qq[4];
#pragma unroll
            for (int r=0;r<4;++r){
                float sx=posx[rbase+r], sy=posy[rbase+r], sz=posz[rbase+r];
                qq[r]=eqb[rbase+r];
                float dx=sx-k0x, dy=sy-k0y, dz=sz-k0z;
                w0[r]=fmaxf(1.f-sqrtf(dx*dx+dy*dy+dz*dz)*INV_EXT,0.f);
                float ex=sx-k1x, ey=sy-k1y, ez=sz-k1z;
                float w1r=fmaxf(1.f-sqrtf(ex*ex+ey*ey+ez*ez)*INV_EXT,0.f);
                w1[r]=has2? w1r : 0.f;
            }
#pragma unroll
            for (int ot=0;ot<4;++ot){
                f32x4 c={0.f,0.f,0.f,0.f};
                c=__builtin_amdgcn_mfma_f32_16x16x32_bf16(a0,B0[2*ot],c,0,0,0);
                c=__builtin_amdgcn_mfma_f32_16x16x32_bf16(a1,B0[2*ot+1],c,0,0,0);
                f32x4 d={0.f,0.f,0.f,0.f};
                if (has2){
                    d=__builtin_amdgcn_mfma_f32_16x16x32_bf16(a0,B1[2*ot],d,0,0,0);
                    d=__builtin_amdgcn_mfma_f32_16x16x32_bf16(a1,B1[2*ot+1],d,0,0,0);
                }
#pragma unroll
                for (int r=0;r<4;++r){
                    float val=w0[r]*c[r]+w1[r]*d[r];
                    if (val!=0.f) atomicAdd(&outacc[qq[r]*OSTR+ot*16+r15], val);
                }
            }
        }
        __syncthreads();
    };

    for (int it=t; it<QB*HN; it+=NTB){
        int q=it>>5, h=it&31, n=nq0+q;
        bool inr=false; int idx=0; float px=0.f,py=0.f,pz=0.f;
        if (n<N){
            idx=inds[(size_t)n*HN+h];
            if ((unsigned)idx<(unsigned)M){
                float sx,sy,sz;
                if (use_ws){ float4 s4=sp4[idx]; sx=s4.x; sy=s4.y; sz=s4.z; }
                else { sx=s_pts[idx*3]; sy=s_pts[idx*3+1]; sz=s_pts[idx*3+2]; }
                px=sx-qls[q*3]; py=sy-qls[q*3+1]; pz=sz-qls[q*3+2];
                inr=(px*px+py*py+pz*pz)<=CUT2;
            }
        }
        if (inr){
            int sl=atomicAdd(&cnt,1);
            if (sl<CAPB){ eqb[sl]=q; eidxb[sl]=idx; posx[sl]=px; posy[sl]=py; posz[sl]=pz; }
        }
    }
    __syncthreads();
    const int total=cnt;

    if (total<=CAPB){
        process(total);
    } else {
        for (int w=0; w<(QB*HN)/64; ++w){
            __syncthreads();
            if (t==0) cnt=0;
            __syncthreads();
            if (t<64){
                int pair=w*64+t;
                int q=pair>>5, h=pair&31, n=nq0+q;
                if (n<N){
                    int idx=inds[(size_t)n*HN+h];
                    if ((unsigned)idx<(unsigned)M){
                        float sx,sy,sz;
                        if (use_ws){ float4 s4=sp4[idx]; sx=s4.x; sy=s4.y; sz=s4.z; }
                        else { sx=s_pts[idx*3]; sy=s_pts[idx*3+1]; sz=s_pts[idx*3+2]; }
                        float px=sx-qls[q*3], py=sy-qls[q*3+1], pz=sz-qls[q*3+2];
                        if (px*px+py*py+pz*pz<=CUT2){
                            int sl=atomicAdd(&cnt,1);
                            eqb[sl]=q; eidxb[sl]=idx; posx[sl]=px; posy[sl]=py; posz[sl]=pz;
                        }
                    }
                }
            }
            __syncthreads();
            process(cnt);
        }
    }
    __syncthreads();

    for (int j=t; j<QB*CIN; j+=NTB){
        int q=j>>6, o=j&63, n=nq0+q;
        if (n<N) out[(size_t)n*CIN+o]=outacc[q*OSTR+o];
    }
}

extern "C" void kernel_launch(void* const* d_in, const int* in_sizes, int n_in,
                              void* d_out, int out_size, void* d_ws, size_t ws_size,
                              hipStream_t stream)
{
    const float* q_pts=(const float*)d_in[0];
    const float* s_pts=(const float*)d_in[1];
    const int*   inds =(const int*)d_in[2];
    const float* x    =(const float*)d_in[3];
    const float* W    =(const float*)d_in[4];
    const float* kpts =(const float*)d_in[5];
    float* outp=(float*)d_out;
    int N=in_sizes[0]/3;
    int M=in_sizes[1]/3;

    char* wsb=(char*)d_ws;
    float4* sp4=(float4*)wsb;
    unsigned short* Wt2=(unsigned short*)(wsb + (size_t)M*16);

    const size_t WT2B = (size_t)KP*8*64*8*2;            // 221184
    size_t need = (size_t)M*16 + WT2B;

    if (ws_size >= need){
        int prepN = (M > KP*8*64) ? M : KP*8*64;
        hipLaunchKernelGGL(kp_prep2, dim3((prepN+255)/256), dim3(256), 0, stream,
                           s_pts, W, sp4, Wt2, M);
        int nblocks = (N + QB2 - 1) / QB2;
        hipLaunchKernelGGL(kpconv_fused, dim3(nblocks), dim3(256), 0, stream,
                           q_pts, inds, x, kpts, sp4, Wt2, outp, N, M);
        return;
    }

    // fallback: no workspace
    hipLaunchKernelGGL(kpconv6, dim3((N+QB-1)/QB), dim3(NTB), 0, stream,
                       q_pts, s_pts, inds, x, W, kpts, sp4, Wt2, 0, outp, N, M);
}